// Round 3
// baseline (48.394 us; speedup 1.0000x reference)
//
#include <hip/hip_runtime.h>
#include <math.h>

#define NPTS 8192
#define NB 4
#define SCALE (1.0f/32.0f)
#define CHUNK 2048
#define NCHUNK 4
#define GRID 512            // NB * 2 dirs * 64 i-blocks

typedef _Float16 half4 __attribute__((ext_vector_type(4)));
typedef float float16 __attribute__((ext_vector_type(16)));
typedef unsigned long long u64;
typedef unsigned int u32;
union H4 { half4 h; u64 u; };

// Two-term f16 split of the b-side Gram vector: u = -2*b', w = |b'|^2.
// k-terms (K=8): [uxh,uxl,uxh,uyh | uyl,uyh,wh,wl] paired against
// a-side       : [axh,axh,axl,ayh | ayh,ayl, 1, 1]
// so sum_k = -2(ax*bx+ay*by) + |b'|^2 = d2' - a2'  (exact to ~2^-22 rel).
__device__ __forceinline__ void bsplit(float x, float y, u64& lo, u64& hi) {
    float xs = x * SCALE, ys = y * SCALE;
    float ux = -2.0f * xs, uy = -2.0f * ys;
    _Float16 uxh = (_Float16)ux; _Float16 uxl = (_Float16)(ux - (float)uxh);
    _Float16 uyh = (_Float16)uy; _Float16 uyl = (_Float16)(uy - (float)uyh);
    float w = fmaf(xs, xs, ys * ys);
    _Float16 wh = (_Float16)w;  _Float16 wl = (_Float16)(w - (float)wh);
    H4 l, h;
    l.h = (half4){uxh, uxl, uxh, uyh};
    h.h = (half4){uyl, uyh, wh, wl};
    lo = l.u; hi = h.u;
}

// One block = (batch, dir, 128 a-points). Iterates ALL 8192 b-points in 4
// LDS chunks; per-a-point min finished in-block; one atomicMax per block;
// last block computes the final scalar (ticket pattern).
__global__ __launch_bounds__(256) void haus_main(
    const float* __restrict__ pred, const float* __restrict__ targ,
    u32* __restrict__ hm /*[8]*/, u32* __restrict__ ticket,
    float* __restrict__ out)
{
    __shared__ u64 sL[2 * CHUNK];      // [khalf][point] b-side frags, 32 KB
    __shared__ float smax[4];

    int bid = blockIdx.x;
    int iblk = bid & 63;  bid >>= 6;
    int dir  = bid & 1;   bid >>= 1;
    int batch = bid;

    int tid = threadIdx.x;
    int wave = tid >> 6, lane = tid & 63;
    int lr = lane & 31, lh = lane >> 5;

    const float* A  = dir ? targ : pred;
    const float* Bp = dir ? pred : targ;
    const float2* ain = (const float2*)A + (size_t)batch * NPTS;
    const float4* bin = (const float4*)((const float2*)Bp + (size_t)batch * NPTS);

    // a-side fragment: lane (lr,lh) holds k-half lh of a-point i
    int i = iblk * 128 + wave * 32 + lr;
    float2 ap = ain[i];
    float axs = ap.x * SCALE, ays = ap.y * SCALE;
    _Float16 axh = (_Float16)axs; _Float16 axl = (_Float16)(axs - (float)axh);
    _Float16 ayh = (_Float16)ays; _Float16 ayl = (_Float16)(ays - (float)ayh);
    H4 r;
    if (lh == 0) r.h = (half4){axh, axh, axl, ayh};
    else         r.h = (half4){ayh, ayl, (_Float16)1.0f, (_Float16)1.0f};
    half4 R = r.h;
    float a2 = fmaf(axs, axs, ays * ays);

    const float16 z = {};
    float mn = 3.0e38f;

    for (int c = 0; c < NCHUNK; ++c) {
        __syncthreads();               // previous chunk's readers done
        #pragma unroll
        for (int it = 0; it < 4; ++it) {
            int idx = it * 256 + tid;  // float4 index within chunk (2 pts)
            float4 p = bin[c * (CHUNK/2) + idx];
            u64 lo, hi;
            bsplit(p.x, p.y, lo, hi);
            sL[2*idx]             = lo;
            sL[CHUNK + 2*idx]     = hi;
            bsplit(p.z, p.w, lo, hi);
            sL[2*idx + 1]         = lo;
            sL[CHUNK + 2*idx + 1] = hi;
        }
        __syncthreads();

        const u64* lp = &sL[lh * CHUNK + lr];
        #pragma unroll 4
        for (int jt = 0; jt < CHUNK/32; ++jt) {
            H4 L; L.u = lp[jt * 32];
            // D[j_row][i_col]: 32 b-points x 32 a-points; lane holds 16 rows
            float16 acc = __builtin_amdgcn_mfma_f32_32x32x8f16(L.h, R, z, 0, 0, 0);
            // 17-input min tree (8 x v_min3_f32 after fusion)
            float m0 = fminf(fminf(acc[0],  acc[1]),  acc[2]);
            float m1 = fminf(fminf(acc[3],  acc[4]),  acc[5]);
            float m2 = fminf(fminf(acc[6],  acc[7]),  acc[8]);
            float m3 = fminf(fminf(acc[9],  acc[10]), acc[11]);
            float m4 = fminf(fminf(acc[12], acc[13]), acc[14]);
            float t0 = fminf(fminf(m0, m1), m2);
            float t1 = fminf(fminf(m3, m4), acc[15]);
            mn = fminf(fminf(t0, t1), mn);
        }
    }

    // merge the two lane halves (other 16 j-rows of the same a-point)
    mn = fminf(mn, __shfl_xor(mn, 32));
    float v = fmaxf(mn + a2, 0.0f);    // add back a2', clamp (scaled d^2)

    // max over the wave's 32 a-points
    #pragma unroll
    for (int o = 16; o; o >>= 1) v = fmaxf(v, __shfl_xor(v, o));
    if (lane == 0) smax[wave] = v;
    __syncthreads();

    if (tid == 0) {
        float bm = fmaxf(fmaxf(smax[0], smax[1]), fmaxf(smax[2], smax[3]));
        atomicMax(&hm[batch * 2 + dir], __float_as_uint(bm));
        __threadfence();                       // release hmax update
        u32 done = atomicAdd(ticket, 1);
        if (done == GRID - 1) {                // last block finalizes
            __threadfence();                   // acquire all hmax updates
            float s = 0.0f;
            #pragma unroll
            for (int b = 0; b < NB; ++b) {
                float h0 = __uint_as_float(atomicMax(&hm[2*b],     0u));
                float h1 = __uint_as_float(atomicMax(&hm[2*b + 1], 0u));
                s += sqrtf(fmaxf(h0, h1));
            }
            out[0] = s * (32.0f / NB);         // unscale, mean over batches
        }
    }
}

extern "C" void kernel_launch(void* const* d_in, const int* in_sizes, int n_in,
                              void* d_out, int out_size, void* d_ws, size_t ws_size,
                              hipStream_t stream) {
    const float* pred = (const float*)d_in[0];   // [4,8192,2] f32
    const float* targ = (const float*)d_in[1];   // [4,8192,2] f32

    u32* hm     = (u32*)d_ws;        // 8 max-bits (non-negative float bits)
    u32* ticket = hm + 8;

    hipMemsetAsync(d_ws, 0, 64, stream);         // zero hm + ticket
    hipLaunchKernelGGL(haus_main, dim3(GRID), dim3(256), 0, stream,
                       pred, targ, hm, ticket, (float*)d_out);
}